// Round 16
// baseline (47.002 us; speedup 1.0000x reference)
//
#include <hip/hip_runtime.h>
#include <hip/hip_bf16.h>
#include <math.h>

// Problem constants
constexpr int kB  = 8;
constexpr int kTD = 128;
constexpr int kTE = 256;
constexpr int kH  = 512;

constexpr float kTwoLog2e = 2.8853900817779268f; // 2*log2(e)
constexpr float kLog2e    = 1.4426950408889634f;

constexpr int TM = 2;              // t-tile in fused kernel (r16: was 4)
constexpr int GEMM_BLOCKS = 192;   // 24 m-pair-tiles (16 enc + 8 dec) x 8 n-tiles

typedef __attribute__((ext_vector_type(8)))  short short8;   // 8 bf16 (4 VGPRs)
typedef __attribute__((ext_vector_type(16))) float f32x16;   // 32x32 acc

// round-to-nearest-even f32 -> bf16 (bit manip; no NaN inputs here)
__device__ __forceinline__ unsigned short f2bf(float x) {
    unsigned int u = __float_as_uint(x);
    return (unsigned short)((u + 0x7fffu + ((u >> 16) & 1u)) >> 16);
}
__device__ __forceinline__ float bf2f(unsigned short h) {
    return __uint_as_float(((unsigned int)h) << 16);
}

// ---------------------------------------------------------------------------
// Kernel 1 (prep): both GEMMs via split-bf16 MFMA (Ahi*Whi + Ahi*Wlo + Alo*Whi)
// r14 structure VERBATIM (proven best, 42.4 us): 512-thread blocks own TWO
// 64-row m-tiles sharing ONE W-tile stream; 193 blocks = one balanced pass.
//   enc rows: fp32 ewt[b][h>>2][s][h&3]   (r15's bf16-E was neutral -> reverted)
//   dec rows: row-major dwc[t][h]
// ---------------------------------------------------------------------------
__global__ __launch_bounds__(512)
void prep_kernel(const float* __restrict__ enc, const float* __restrict__ dec,
                 const float* __restrict__ W1, const float* __restrict__ W2,
                 const void* __restrict__ mask_raw,
                 float* __restrict__ ewt, float* __restrict__ dwc,
                 float* __restrict__ mask_f) {
    const int bx = blockIdx.x;
    const int tid = threadIdx.x;

    if (bx == GEMM_BLOCKS) {
        // ---- mask decode (layout auto-detect: int32 / byte / float) ----
        const unsigned int* w = (const unsigned int*)mask_raw;
        unsigned int gt1 = 0, flt = 0;
        if (tid < 512) {                    // first 2048B safe under every layout
            unsigned int v = w[tid];
            if (v == 0x3f800000u) flt = 1;
            else if (v > 1u) gt1 = 1;
        }
        __shared__ unsigned int s_gt1, s_flt;
        if (tid == 0) { s_gt1 = 0u; s_flt = 0u; }
        __syncthreads();
        if (gt1) atomicOr(&s_gt1, 1u);
        if (flt) atomicOr(&s_flt, 1u);
        __syncthreads();
        const int mode = s_flt ? 2 : (s_gt1 ? 1 : 0);
        for (int i = tid; i < kB * kTE; i += 512) {
            float val;
            if (mode == 2)      val = ((const float*)mask_raw)[i];
            else if (mode == 1) val = (float)(((const unsigned char*)mask_raw)[i]);
            else                val = (float)(((const int*)mask_raw)[i]);
            mask_f[i] = val;
        }
        return;
    }

    const int pt = bx >> 3;            // 0..23 m-pair-tile
    const int nt = bx & 7;             // 0..7  n-tile
    const bool is_enc = (pt < 16);
    const int mt0 = is_enc ? (pt * 2) : (32 + (pt - 16) * 2);
    const int n0 = nt * 64;

    const int g   = tid >> 8;          // group 0/1 -> own m-tile
    const int lid = tid & 255;
    const int mt  = mt0 + g;
    const int m0  = mt * 64;           // global row (enc rows 0..2047, dec 2048..)
    const float* Abase = is_enc ? (enc + (size_t)m0 * kH)
                                : (dec + (size_t)(m0 - 2048) * kH);
    const float* W = is_enc ? W1 : W2;

    // LDS: per-group A hi/lo tiles + ONE shared W tile (pitch 40 ushorts)
    __shared__ __align__(16) unsigned short Ahi[2][64][40], Alo[2][64][40];
    __shared__ __align__(16) unsigned short Bhi[64][40], Blo[64][40];
    __shared__ float Ws[32][68];       // fp32 W-tile for in-LDS transpose

    const int lane = tid & 63;
    const int gw   = (tid >> 6) & 3;   // wave within group
    const int wr   = gw >> 1, wc = gw & 1;
    const int col  = lane & 31, hi5 = lane >> 5;

    // staging roles
    const int ar  = lid >> 2;          // A: row 0..63 (per group)
    const int akc = (lid & 3) * 8;     // A: k-chunk of 8
    const int wkr = tid >> 4;          // W pass1: k-row 0..31 (512 thr, 1 float4)
    const int wnc = (tid & 15) * 4;    // W pass1: n-chunk of 4
    const int pn  = tid & 63;          // W pass2: n 0..63 (lane-consecutive!)
    const int pkc = ((tid >> 6) & 3) * 8; // W pass2: k-chunk of 8 (tid<256)

    f32x16 acc = {};

    // preload step 0
    float4 a0p = *(const float4*)&Abase[(size_t)ar * kH + akc];
    float4 a1p = *(const float4*)&Abase[(size_t)ar * kH + akc + 4];
    float4 w0p = *(const float4*)&W[(size_t)wkr * kH + n0 + wnc];

    for (int step = 0; step < 16; ++step) {
        // ---- stage W fp32 (pass1, whole block) + A hi/lo (per group) ----
        *(float4*)&Ws[wkr][wnc] = w0p;
        {
            uint4 H, L;
            float f[8] = {a0p.x, a0p.y, a0p.z, a0p.w, a1p.x, a1p.y, a1p.z, a1p.w};
            unsigned short hs[8], ls[8];
            #pragma unroll
            for (int j = 0; j < 8; ++j) {
                hs[j] = f2bf(f[j]);
                ls[j] = f2bf(f[j] - bf2f(hs[j]));
            }
            H.x = hs[0] | (hs[1] << 16); H.y = hs[2] | (hs[3] << 16);
            H.z = hs[4] | (hs[5] << 16); H.w = hs[6] | (hs[7] << 16);
            L.x = ls[0] | (ls[1] << 16); L.y = ls[2] | (ls[3] << 16);
            L.z = ls[4] | (ls[5] << 16); L.w = ls[6] | (ls[7] << 16);
            *(uint4*)&Ahi[g][ar][akc] = H;
            *(uint4*)&Alo[g][ar][akc] = L;
        }
        __syncthreads();

        // ---- W pass2 (tid<256): transpose-read columns, split, K-major ----
        if (tid < 256) {
            uint4 H, L;
            unsigned short hs[8], ls[8];
            #pragma unroll
            for (int j = 0; j < 8; ++j) {
                float x = Ws[pkc + j][pn];
                hs[j] = f2bf(x);
                ls[j] = f2bf(x - bf2f(hs[j]));
            }
            H.x = hs[0] | (hs[1] << 16); H.y = hs[2] | (hs[3] << 16);
            H.z = hs[4] | (hs[5] << 16); H.w = hs[6] | (hs[7] << 16);
            L.x = ls[0] | (ls[1] << 16); L.y = ls[2] | (ls[3] << 16);
            L.z = ls[4] | (ls[5] << 16); L.w = ls[6] | (ls[7] << 16);
            *(uint4*)&Bhi[pn][pkc] = H;
            *(uint4*)&Blo[pn][pkc] = L;
        }

        // prefetch next step's globals (land during MFMA phase)
        if (step < 15) {
            const int k1 = (step + 1) * 32;
            a0p = *(const float4*)&Abase[(size_t)ar * kH + k1 + akc];
            a1p = *(const float4*)&Abase[(size_t)ar * kH + k1 + akc + 4];
            w0p = *(const float4*)&W[(size_t)(k1 + wkr) * kH + n0 + wnc];
        }
        __syncthreads();

        // ---- fragments + MFMA: 2 k-chunks x 3 split-products ----
        #pragma unroll
        for (int kc = 0; kc < 32; kc += 16) {
            const int ka = kc + hi5 * 8;
            short8 ah = *(const short8*)&Ahi[g][wr * 32 + col][ka];
            short8 al = *(const short8*)&Alo[g][wr * 32 + col][ka];
            short8 bh = *(const short8*)&Bhi[wc * 32 + col][ka];
            short8 bl = *(const short8*)&Blo[wc * 32 + col][ka];
            acc = __builtin_amdgcn_mfma_f32_32x32x16_bf16(ah, bh, acc, 0, 0, 0);
            acc = __builtin_amdgcn_mfma_f32_32x32x16_bf16(ah, bl, acc, 0, 0, 0);
            acc = __builtin_amdgcn_mfma_f32_32x32x16_bf16(al, bh, acc, 0, 0, 0);
        }
        __syncthreads();   // keep next-step staging off in-flight ds_reads
    }

    // ---- epilogue: exp2 + store (per group) ----
    const int h = n0 + wc * 32 + col;
    if (is_enc) {
        #pragma unroll
        for (int reg = 0; reg < 16; ++reg) {
            const int row = (reg & 3) + 8 * (reg >> 2) + 4 * hi5;
            const int gm = m0 + wr * 32 + row;            // = b*256 + s
            const int bb = gm >> 8, sE = gm & 255;
            float val = __builtin_amdgcn_exp2f(acc[reg] * kTwoLog2e);
            ewt[(((size_t)bb * 128 + (h >> 2)) * 256 + sE) * 4 + (h & 3)] = val;
        }
    } else {
        #pragma unroll
        for (int reg = 0; reg < 16; ++reg) {
            const int row = (reg & 3) + 8 * (reg >> 2) + 4 * hi5;
            const int dm = (m0 - 2048) + wr * 32 + row;   // = b*128 + t
            float val = __builtin_amdgcn_exp2f(acc[reg] * kTwoLog2e);
            dwc[(size_t)dm * kH + h] = val;
        }
    }
}

// ---------------------------------------------------------------------------
// Kernel 2 (fused): scores -> softmax -> context.
//   r16 CHANGE: TM=2 -> 512 blocks (2 per CU co-resident). LDS ~18KB and
//   VGPR<=64 so two 1024-thread blocks fit a CU (2048 thr = cap, 32 waves).
//   Rationale: every variant since r3 ran 1 block/CU; the serial
//   score->softmax->context phases stall the whole CU at each barrier
//   (occupancy pinned 33-40%). Two co-resident blocks interleave phases.
//   Structure per block is the r8 form with TM=2 (s=tid&255, hq=tid>>8).
// ---------------------------------------------------------------------------
__global__ __launch_bounds__(1024, 8)
void fused_attn_kernel(const float* __restrict__ ewt, const float* __restrict__ dwc,
                       const float* __restrict__ enc, const float* __restrict__ V,
                       const float* __restrict__ mask_f,
                       float* __restrict__ ctx_out, float* __restrict__ attn_out) {
    const int bid = blockIdx.x;
    const int b   = bid & 7;            // XCD-pinned batch
    const int t0  = (bid >> 3) * TM;
    const int tid = threadIdx.x;
    const int s   = tid & 255;
    const int hq  = tid >> 8;           // 0..3 (128 h each)
    const int hqu = __builtin_amdgcn_readfirstlane(hq);  // wave-uniform

    __shared__ union {
        float  part[3 * TM * kTE];      // 6KB score partials
        float4 pctx[4][TM][128];        // 16KB context partial tree
    } u;
    __shared__ float2 wgt2[kTE];        // 2KB softmax weights, t-major
    __shared__ float red_mx[4][TM], red_sm[4][TM];

    // ---- score phase over this thread's 128-h quarter ----
    const float4* E4 = (const float4*)ewt + ((size_t)(b * 128 + hqu * 32) * 256 + s);
    const float4* Pb = (const float4*)(dwc + (size_t)(b * kTD + t0) * kH) + hqu * 32;
    const float4* V4 = (const float4*)V + hqu * 32;

    float a0 = 0.0f, a1 = 0.0f;
    #pragma unroll 4
    for (int g = 0; g < 32; ++g) {
        float4 e  = E4[(size_t)g * 256];
        float4 vv = V4[g];
        {   float4 q = Pb[g];
            float A_ = fmaf(e.x, q.x, 1.0f), B_ = fmaf(e.y, q.y, 1.0f);
            float C_ = fmaf(e.z, q.z, 1.0f), D_ = fmaf(e.w, q.w, 1.0f);
            float t1 = fmaf(vv.y, A_, vv.x * B_);
            float t2 = fmaf(vv.w, C_, vv.z * D_);
            float AB = A_ * B_, CD = C_ * D_;
            float num = fmaf(t2, AB, t1 * CD);
            a0 = fmaf(num, __builtin_amdgcn_rcpf(AB * CD), a0); }
        {   float4 q = Pb[128 + g];
            float A_ = fmaf(e.x, q.x, 1.0f), B_ = fmaf(e.y, q.y, 1.0f);
            float C_ = fmaf(e.z, q.z, 1.0f), D_ = fmaf(e.w, q.w, 1.0f);
            float t1 = fmaf(vv.y, A_, vv.x * B_);
            float t2 = fmaf(vv.w, C_, vv.z * D_);
            float AB = A_ * B_, CD = C_ * D_;
            float num = fmaf(t2, AB, t1 * CD);
            a1 = fmaf(num, __builtin_amdgcn_rcpf(AB * CD), a1); }
    }

    if (hq > 0) {
        float* pp = &u.part[(hq - 1) * TM * kTE];
        pp[0 * kTE + s] = a0; pp[1 * kTE + s] = a1;
    }
    __syncthreads();

    const bool active = (hq == 0);
    const int wvq = s >> 6;
    float sc0, sc1;
    if (active) {
        const float* P = u.part;
        const float pen = (1.0f - mask_f[b * kTE + s]) * -1e9f;
        sc0 = -2.0f * ((a0 + P[0 * TM * kTE + 0 * kTE + s]) +
                       (P[1 * TM * kTE + 0 * kTE + s] + P[2 * TM * kTE + 0 * kTE + s])) + pen;
        sc1 = -2.0f * ((a1 + P[0 * TM * kTE + 1 * kTE + s]) +
                       (P[1 * TM * kTE + 1 * kTE + s] + P[2 * TM * kTE + 1 * kTE + s])) + pen;
        float m0 = sc0, m1 = sc1;
        #pragma unroll
        for (int off = 1; off < 64; off <<= 1) {
            m0 = fmaxf(m0, __shfl_xor(m0, off));
            m1 = fmaxf(m1, __shfl_xor(m1, off));
        }
        if ((s & 63) == 0) {
            red_mx[wvq][0] = m0; red_mx[wvq][1] = m1;
        }
    }
    __syncthreads();

    float p0, p1;
    if (active) {
        float m0 = fmaxf(fmaxf(red_mx[0][0], red_mx[1][0]), fmaxf(red_mx[2][0], red_mx[3][0]));
        float m1 = fmaxf(fmaxf(red_mx[0][1], red_mx[1][1]), fmaxf(red_mx[2][1], red_mx[3][1]));
        p0 = __builtin_amdgcn_exp2f((sc0 - m0) * kLog2e);
        p1 = __builtin_amdgcn_exp2f((sc1 - m1) * kLog2e);
        float s0 = p0, s1 = p1;
        #pragma unroll
        for (int off = 1; off < 64; off <<= 1) {
            s0 += __shfl_xor(s0, off);
            s1 += __shfl_xor(s1, off);
        }
        if ((s & 63) == 0) {
            red_sm[wvq][0] = s0; red_sm[wvq][1] = s1;
        }
    }
    __syncthreads();

    if (active) {
        float s0 = (red_sm[0][0] + red_sm[1][0]) + (red_sm[2][0] + red_sm[3][0]);
        float s1 = (red_sm[0][1] + red_sm[1][1]) + (red_sm[2][1] + red_sm[3][1]);
        float2 w;
        w.x = p0 * __builtin_amdgcn_rcpf(s0);
        w.y = p1 * __builtin_amdgcn_rcpf(s1);
        wgt2[s] = w;
        float* ao = attn_out + (size_t)(b * kTD + t0) * kTE + s;
        ao[0]   = w.x;
        ao[kTE] = w.y;
    }
    __syncthreads();

    // ---- context phase: thread = (h-float4, s-octant); float4 loads ----
    const int th4 = tid & 127;           // h quad 0..127
    const int sq  = tid >> 7;            // s octant 0..7
    const float4* enc4 = (const float4*)(enc + (size_t)b * kTE * kH);
    float4 c[TM];
    #pragma unroll
    for (int t = 0; t < TM; ++t) c[t] = float4{0.f, 0.f, 0.f, 0.f};
    #pragma unroll 4
    for (int i = 0; i < 32; ++i) {
        const int ss = sq * 32 + i;
        float4 e = enc4[(size_t)ss * 128 + th4];
        float2 w = wgt2[ss];
        c[0].x = fmaf(w.x, e.x, c[0].x); c[0].y = fmaf(w.x, e.y, c[0].y);
        c[0].z = fmaf(w.x, e.z, c[0].z); c[0].w = fmaf(w.x, e.w, c[0].w);
        c[1].x = fmaf(w.y, e.x, c[1].x); c[1].y = fmaf(w.y, e.y, c[1].y);
        c[1].z = fmaf(w.y, e.z, c[1].z); c[1].w = fmaf(w.y, e.w, c[1].w);
    }
    // tree combine: 8 -> 4 -> 1
    if (sq >= 4) {
        #pragma unroll
        for (int t = 0; t < TM; ++t) u.pctx[sq - 4][t][th4] = c[t];
    }
    __syncthreads();
    if (sq < 4) {
        #pragma unroll
        for (int t = 0; t < TM; ++t) {
            float4 p = u.pctx[sq][t][th4];
            c[t].x += p.x; c[t].y += p.y; c[t].z += p.z; c[t].w += p.w;
        }
    }
    __syncthreads();
    if (sq >= 1 && sq < 4) {
        #pragma unroll
        for (int t = 0; t < TM; ++t) u.pctx[sq - 1][t][th4] = c[t];
    }
    __syncthreads();
    if (sq == 0) {
        #pragma unroll
        for (int t = 0; t < TM; ++t) {
            float4 q0v = u.pctx[0][t][th4];
            float4 q1v = u.pctx[1][t][th4];
            float4 q2v = u.pctx[2][t][th4];
            c[t].x += (q0v.x + q1v.x) + q2v.x;
            c[t].y += (q0v.y + q1v.y) + q2v.y;
            c[t].z += (q0v.z + q1v.z) + q2v.z;
            c[t].w += (q0v.w + q1v.w) + q2v.w;
            *(float4*)&ctx_out[(size_t)(b * kTD + t0 + t) * kH + th4 * 4] = c[t];
        }
    }
}

// ---------------------------------------------------------------------------
extern "C" void kernel_launch(void* const* d_in, const int* in_sizes, int n_in,
                              void* d_out, int out_size, void* d_ws, size_t ws_size,
                              hipStream_t stream) {
    const float* enc  = (const float*)d_in[0];   // [B, TE, H]
    const float* dec  = (const float*)d_in[1];   // [B, TD, H]
    const void*  mask = d_in[2];                 // [B, TE] bool
    const float* W1   = (const float*)d_in[3];
    const float* W2   = (const float*)d_in[4];
    const float* V    = (const float*)d_in[5];   // [H, 1]

    float* ctx_out  = (float*)d_out;                     // [B, TD, H]
    float* attn_out = (float*)d_out + kB * kTD * kH;     // [B, TD, TE]

    char* ws = (char*)d_ws;
    float* mask_f = (float*)ws;                                      // 2048 f
    float* ewt    = (float*)(ws + 8192);                             // E^T packed [b][h/4][s][4]
    float* dwc    = (float*)(ws + 8192 + (size_t)kB * kTE * kH * 4); // P[t][h]

    hipLaunchKernelGGL(prep_kernel, dim3(GEMM_BLOCKS + 1), dim3(512), 0, stream,
                       enc, dec, W1, W2, mask, ewt, dwc, mask_f);
    hipLaunchKernelGGL(fused_attn_kernel, dim3(kB * kTD / TM), dim3(1024), 0, stream,
                       ewt, dwc, enc, V, mask_f, ctx_out, attn_out);
}

// Round 17
// 42.139 us; speedup vs baseline: 1.1154x; 1.1154x over previous
//
#include <hip/hip_runtime.h>
#include <hip/hip_bf16.h>
#include <math.h>

// Problem constants
constexpr int kB  = 8;
constexpr int kTD = 128;
constexpr int kTE = 256;
constexpr int kH  = 512;

constexpr float kTwoLog2e = 2.8853900817779268f; // 2*log2(e)
constexpr float kLog2e    = 1.4426950408889634f;

constexpr int TM = 4;              // t-tile in fused kernel
constexpr int GEMM_BLOCKS = 192;   // 24 m-pair-tiles (16 enc + 8 dec) x 8 n-tiles

typedef __attribute__((ext_vector_type(8)))  short short8;   // 8 bf16 (4 VGPRs)
typedef __attribute__((ext_vector_type(16))) float f32x16;   // 32x32 acc

// round-to-nearest-even f32 -> bf16 (bit manip; no NaN inputs here)
__device__ __forceinline__ unsigned short f2bf(float x) {
    unsigned int u = __float_as_uint(x);
    return (unsigned short)((u + 0x7fffu + ((u >> 16) & 1u)) >> 16);
}
__device__ __forceinline__ float bf2f(unsigned short h) {
    return __uint_as_float(((unsigned int)h) << 16);
}

// ---------------------------------------------------------------------------
// Kernel 1 (prep): both GEMMs via split-bf16 MFMA (Ahi*Whi + Ahi*Wlo + Alo*Whi)
// r14 structure (proven best, 42.4 us): 512-thread blocks own TWO 64-row
// m-tiles sharing ONE W-tile stream — W staged+transposed+split once per
// block; 193 blocks = one balanced pass over 256 CUs.
//   enc rows: fp32 ewt[b][h>>2][s][h&3]
//   dec rows: row-major dwc[t][h]
// ---------------------------------------------------------------------------
__global__ __launch_bounds__(512)
void prep_kernel(const float* __restrict__ enc, const float* __restrict__ dec,
                 const float* __restrict__ W1, const float* __restrict__ W2,
                 const void* __restrict__ mask_raw,
                 float* __restrict__ ewt, float* __restrict__ dwc,
                 float* __restrict__ mask_f) {
    const int bx = blockIdx.x;
    const int tid = threadIdx.x;

    if (bx == GEMM_BLOCKS) {
        // ---- mask decode (layout auto-detect: int32 / byte / float) ----
        const unsigned int* w = (const unsigned int*)mask_raw;
        unsigned int gt1 = 0, flt = 0;
        if (tid < 512) {                    // first 2048B safe under every layout
            unsigned int v = w[tid];
            if (v == 0x3f800000u) flt = 1;
            else if (v > 1u) gt1 = 1;
        }
        __shared__ unsigned int s_gt1, s_flt;
        if (tid == 0) { s_gt1 = 0u; s_flt = 0u; }
        __syncthreads();
        if (gt1) atomicOr(&s_gt1, 1u);
        if (flt) atomicOr(&s_flt, 1u);
        __syncthreads();
        const int mode = s_flt ? 2 : (s_gt1 ? 1 : 0);
        for (int i = tid; i < kB * kTE; i += 512) {
            float val;
            if (mode == 2)      val = ((const float*)mask_raw)[i];
            else if (mode == 1) val = (float)(((const unsigned char*)mask_raw)[i]);
            else                val = (float)(((const int*)mask_raw)[i]);
            mask_f[i] = val;
        }
        return;
    }

    const int pt = bx >> 3;            // 0..23 m-pair-tile
    const int nt = bx & 7;             // 0..7  n-tile
    const bool is_enc = (pt < 16);
    const int mt0 = is_enc ? (pt * 2) : (32 + (pt - 16) * 2);
    const int n0 = nt * 64;

    const int g   = tid >> 8;          // group 0/1 -> own m-tile
    const int lid = tid & 255;
    const int mt  = mt0 + g;
    const int m0  = mt * 64;           // global row (enc rows 0..2047, dec 2048..)
    const float* Abase = is_enc ? (enc + (size_t)m0 * kH)
                                : (dec + (size_t)(m0 - 2048) * kH);
    const float* W = is_enc ? W1 : W2;

    // LDS: per-group A hi/lo tiles + ONE shared W tile (pitch 40 ushorts)
    __shared__ __align__(16) unsigned short Ahi[2][64][40], Alo[2][64][40];
    __shared__ __align__(16) unsigned short Bhi[64][40], Blo[64][40];
    __shared__ float Ws[32][68];       // fp32 W-tile for in-LDS transpose

    const int lane = tid & 63;
    const int gw   = (tid >> 6) & 3;   // wave within group
    const int wr   = gw >> 1, wc = gw & 1;
    const int col  = lane & 31, hi5 = lane >> 5;

    // staging roles
    const int ar  = lid >> 2;          // A: row 0..63 (per group)
    const int akc = (lid & 3) * 8;     // A: k-chunk of 8
    const int wkr = tid >> 4;          // W pass1: k-row 0..31 (512 thr, 1 float4)
    const int wnc = (tid & 15) * 4;    // W pass1: n-chunk of 4
    const int pn  = tid & 63;          // W pass2: n 0..63 (lane-consecutive!)
    const int pkc = ((tid >> 6) & 3) * 8; // W pass2: k-chunk of 8 (tid<256)

    f32x16 acc = {};

    // preload step 0
    float4 a0p = *(const float4*)&Abase[(size_t)ar * kH + akc];
    float4 a1p = *(const float4*)&Abase[(size_t)ar * kH + akc + 4];
    float4 w0p = *(const float4*)&W[(size_t)wkr * kH + n0 + wnc];

    for (int step = 0; step < 16; ++step) {
        // ---- stage W fp32 (pass1, whole block) + A hi/lo (per group) ----
        *(float4*)&Ws[wkr][wnc] = w0p;
        {
            uint4 H, L;
            float f[8] = {a0p.x, a0p.y, a0p.z, a0p.w, a1p.x, a1p.y, a1p.z, a1p.w};
            unsigned short hs[8], ls[8];
            #pragma unroll
            for (int j = 0; j < 8; ++j) {
                hs[j] = f2bf(f[j]);
                ls[j] = f2bf(f[j] - bf2f(hs[j]));
            }
            H.x = hs[0] | (hs[1] << 16); H.y = hs[2] | (hs[3] << 16);
            H.z = hs[4] | (hs[5] << 16); H.w = hs[6] | (hs[7] << 16);
            L.x = ls[0] | (ls[1] << 16); L.y = ls[2] | (ls[3] << 16);
            L.z = ls[4] | (ls[5] << 16); L.w = ls[6] | (ls[7] << 16);
            *(uint4*)&Ahi[g][ar][akc] = H;
            *(uint4*)&Alo[g][ar][akc] = L;
        }
        __syncthreads();

        // ---- W pass2 (tid<256): transpose-read columns, split, K-major ----
        if (tid < 256) {
            uint4 H, L;
            unsigned short hs[8], ls[8];
            #pragma unroll
            for (int j = 0; j < 8; ++j) {
                float x = Ws[pkc + j][pn];
                hs[j] = f2bf(x);
                ls[j] = f2bf(x - bf2f(hs[j]));
            }
            H.x = hs[0] | (hs[1] << 16); H.y = hs[2] | (hs[3] << 16);
            H.z = hs[4] | (hs[5] << 16); H.w = hs[6] | (hs[7] << 16);
            L.x = ls[0] | (ls[1] << 16); L.y = ls[2] | (ls[3] << 16);
            L.z = ls[4] | (ls[5] << 16); L.w = ls[6] | (ls[7] << 16);
            *(uint4*)&Bhi[pn][pkc] = H;
            *(uint4*)&Blo[pn][pkc] = L;
        }

        // prefetch next step's globals (land during MFMA phase)
        if (step < 15) {
            const int k1 = (step + 1) * 32;
            a0p = *(const float4*)&Abase[(size_t)ar * kH + k1 + akc];
            a1p = *(const float4*)&Abase[(size_t)ar * kH + k1 + akc + 4];
            w0p = *(const float4*)&W[(size_t)(k1 + wkr) * kH + n0 + wnc];
        }
        __syncthreads();

        // ---- fragments + MFMA: 2 k-chunks x 3 split-products ----
        #pragma unroll
        for (int kc = 0; kc < 32; kc += 16) {
            const int ka = kc + hi5 * 8;
            short8 ah = *(const short8*)&Ahi[g][wr * 32 + col][ka];
            short8 al = *(const short8*)&Alo[g][wr * 32 + col][ka];
            short8 bh = *(const short8*)&Bhi[wc * 32 + col][ka];
            short8 bl = *(const short8*)&Blo[wc * 32 + col][ka];
            acc = __builtin_amdgcn_mfma_f32_32x32x16_bf16(ah, bh, acc, 0, 0, 0);
            acc = __builtin_amdgcn_mfma_f32_32x32x16_bf16(ah, bl, acc, 0, 0, 0);
            acc = __builtin_amdgcn_mfma_f32_32x32x16_bf16(al, bh, acc, 0, 0, 0);
        }
        __syncthreads();   // keep next-step staging off in-flight ds_reads
    }

    // ---- epilogue: exp2 + store (per group) ----
    const int h = n0 + wc * 32 + col;
    if (is_enc) {
        #pragma unroll
        for (int reg = 0; reg < 16; ++reg) {
            const int row = (reg & 3) + 8 * (reg >> 2) + 4 * hi5;
            const int gm = m0 + wr * 32 + row;            // = b*256 + s
            const int bb = gm >> 8, sE = gm & 255;
            float val = __builtin_amdgcn_exp2f(acc[reg] * kTwoLog2e);
            ewt[(((size_t)bb * 128 + (h >> 2)) * 256 + sE) * 4 + (h & 3)] = val;
        }
    } else {
        #pragma unroll
        for (int reg = 0; reg < 16; ++reg) {
            const int row = (reg & 3) + 8 * (reg >> 2) + 4 * hi5;
            const int dm = (m0 - 2048) + wr * 32 + row;   // = b*128 + t
            float val = __builtin_amdgcn_exp2f(acc[reg] * kTwoLog2e);
            dwc[(size_t)dm * kH + h] = val;
        }
    }
}

// ---------------------------------------------------------------------------
// Kernel 2 (fused): scores -> softmax -> context, one (b, 4-t tile) per block.
//   EXACT round-8 structure — terminal configuration. Falsified axes
//   (r9-r16, all neutral/worse): register budget x2, E-prefetch depth,
//   LDS-P, wave work-remap, bf16-E, XCD write-locality, TM=2 co-residency.
// ---------------------------------------------------------------------------
__global__ __launch_bounds__(1024)
void fused_attn_kernel(const float* __restrict__ ewt, const float* __restrict__ dwc,
                       const float* __restrict__ enc, const float* __restrict__ V,
                       const float* __restrict__ mask_f,
                       float* __restrict__ ctx_out, float* __restrict__ attn_out) {
    const int bid = blockIdx.x;
    const int b   = bid & 7;            // XCD-pinned batch
    const int t0  = (bid >> 3) * TM;
    const int tid = threadIdx.x;
    const int s   = tid & 255;
    const int hq  = tid >> 8;           // 0..3 (128 h each)
    const int hqu = __builtin_amdgcn_readfirstlane(hq);  // wave-uniform

    __shared__ union {
        float  part[3 * TM * kTE];      // 12KB score partials
        float4 pctx[4][TM][128];        // 32KB context partial tree
    } u;
    __shared__ float4 wgt4[kTE];        // 4KB softmax weights, t-major
    __shared__ float red_mx[4][TM], red_sm[4][TM];

    // ---- score phase over this thread's 128-h quarter ----
    const float4* E4 = (const float4*)ewt + ((size_t)(b * 128 + hqu * 32) * 256 + s);
    const float4* Pb = (const float4*)(dwc + (size_t)(b * kTD + t0) * kH) + hqu * 32;
    const float4* V4 = (const float4*)V + hqu * 32;

    float a0 = 0.0f, a1 = 0.0f, a2 = 0.0f, a3 = 0.0f;
    #pragma unroll 4
    for (int g = 0; g < 32; ++g) {
        float4 e  = E4[(size_t)g * 256];
        float4 vv = V4[g];
        {   float4 q = Pb[g];
            float A_ = fmaf(e.x, q.x, 1.0f), B_ = fmaf(e.y, q.y, 1.0f);
            float C_ = fmaf(e.z, q.z, 1.0f), D_ = fmaf(e.w, q.w, 1.0f);
            float t1 = fmaf(vv.y, A_, vv.x * B_);
            float t2 = fmaf(vv.w, C_, vv.z * D_);
            float AB = A_ * B_, CD = C_ * D_;
            float num = fmaf(t2, AB, t1 * CD);
            a0 = fmaf(num, __builtin_amdgcn_rcpf(AB * CD), a0); }
        {   float4 q = Pb[128 + g];
            float A_ = fmaf(e.x, q.x, 1.0f), B_ = fmaf(e.y, q.y, 1.0f);
            float C_ = fmaf(e.z, q.z, 1.0f), D_ = fmaf(e.w, q.w, 1.0f);
            float t1 = fmaf(vv.y, A_, vv.x * B_);
            float t2 = fmaf(vv.w, C_, vv.z * D_);
            float AB = A_ * B_, CD = C_ * D_;
            float num = fmaf(t2, AB, t1 * CD);
            a1 = fmaf(num, __builtin_amdgcn_rcpf(AB * CD), a1); }
        {   float4 q = Pb[256 + g];
            float A_ = fmaf(e.x, q.x, 1.0f), B_ = fmaf(e.y, q.y, 1.0f);
            float C_ = fmaf(e.z, q.z, 1.0f), D_ = fmaf(e.w, q.w, 1.0f);
            float t1 = fmaf(vv.y, A_, vv.x * B_);
            float t2 = fmaf(vv.w, C_, vv.z * D_);
            float AB = A_ * B_, CD = C_ * D_;
            float num = fmaf(t2, AB, t1 * CD);
            a2 = fmaf(num, __builtin_amdgcn_rcpf(AB * CD), a2); }
        {   float4 q = Pb[384 + g];
            float A_ = fmaf(e.x, q.x, 1.0f), B_ = fmaf(e.y, q.y, 1.0f);
            float C_ = fmaf(e.z, q.z, 1.0f), D_ = fmaf(e.w, q.w, 1.0f);
            float t1 = fmaf(vv.y, A_, vv.x * B_);
            float t2 = fmaf(vv.w, C_, vv.z * D_);
            float AB = A_ * B_, CD = C_ * D_;
            float num = fmaf(t2, AB, t1 * CD);
            a3 = fmaf(num, __builtin_amdgcn_rcpf(AB * CD), a3); }
    }

    if (hq > 0) {
        float* pp = &u.part[(hq - 1) * TM * kTE];
        pp[0 * kTE + s] = a0; pp[1 * kTE + s] = a1;
        pp[2 * kTE + s] = a2; pp[3 * kTE + s] = a3;
    }
    __syncthreads();

    const bool active = (hq == 0);
    const int wvq = s >> 6;
    float sc0, sc1, sc2, sc3;
    if (active) {
        const float* P = u.part;
        const float pen = (1.0f - mask_f[b * kTE + s]) * -1e9f;
        sc0 = -2.0f * ((a0 + P[0 * TM * kTE + 0 * kTE + s]) +
                       (P[1 * TM * kTE + 0 * kTE + s] + P[2 * TM * kTE + 0 * kTE + s])) + pen;
        sc1 = -2.0f * ((a1 + P[0 * TM * kTE + 1 * kTE + s]) +
                       (P[1 * TM * kTE + 1 * kTE + s] + P[2 * TM * kTE + 1 * kTE + s])) + pen;
        sc2 = -2.0f * ((a2 + P[0 * TM * kTE + 2 * kTE + s]) +
                       (P[1 * TM * kTE + 2 * kTE + s] + P[2 * TM * kTE + 2 * kTE + s])) + pen;
        sc3 = -2.0f * ((a3 + P[0 * TM * kTE + 3 * kTE + s]) +
                       (P[1 * TM * kTE + 3 * kTE + s] + P[2 * TM * kTE + 3 * kTE + s])) + pen;
        float m0 = sc0, m1 = sc1, m2 = sc2, m3 = sc3;
        #pragma unroll
        for (int off = 1; off < 64; off <<= 1) {
            m0 = fmaxf(m0, __shfl_xor(m0, off));
            m1 = fmaxf(m1, __shfl_xor(m1, off));
            m2 = fmaxf(m2, __shfl_xor(m2, off));
            m3 = fmaxf(m3, __shfl_xor(m3, off));
        }
        if ((s & 63) == 0) {
            red_mx[wvq][0] = m0; red_mx[wvq][1] = m1;
            red_mx[wvq][2] = m2; red_mx[wvq][3] = m3;
        }
    }
    __syncthreads();

    float p0, p1, p2, p3;
    if (active) {
        float m0 = fmaxf(fmaxf(red_mx[0][0], red_mx[1][0]), fmaxf(red_mx[2][0], red_mx[3][0]));
        float m1 = fmaxf(fmaxf(red_mx[0][1], red_mx[1][1]), fmaxf(red_mx[2][1], red_mx[3][1]));
        float m2 = fmaxf(fmaxf(red_mx[0][2], red_mx[1][2]), fmaxf(red_mx[2][2], red_mx[3][2]));
        float m3 = fmaxf(fmaxf(red_mx[0][3], red_mx[1][3]), fmaxf(red_mx[2][3], red_mx[3][3]));
        p0 = __builtin_amdgcn_exp2f((sc0 - m0) * kLog2e);
        p1 = __builtin_amdgcn_exp2f((sc1 - m1) * kLog2e);
        p2 = __builtin_amdgcn_exp2f((sc2 - m2) * kLog2e);
        p3 = __builtin_amdgcn_exp2f((sc3 - m3) * kLog2e);
        float s0 = p0, s1 = p1, s2 = p2, s3 = p3;
        #pragma unroll
        for (int off = 1; off < 64; off <<= 1) {
            s0 += __shfl_xor(s0, off);
            s1 += __shfl_xor(s1, off);
            s2 += __shfl_xor(s2, off);
            s3 += __shfl_xor(s3, off);
        }
        if ((s & 63) == 0) {
            red_sm[wvq][0] = s0; red_sm[wvq][1] = s1;
            red_sm[wvq][2] = s2; red_sm[wvq][3] = s3;
        }
    }
    __syncthreads();

    if (active) {
        float s0 = (red_sm[0][0] + red_sm[1][0]) + (red_sm[2][0] + red_sm[3][0]);
        float s1 = (red_sm[0][1] + red_sm[1][1]) + (red_sm[2][1] + red_sm[3][1]);
        float s2 = (red_sm[0][2] + red_sm[1][2]) + (red_sm[2][2] + red_sm[3][2]);
        float s3 = (red_sm[0][3] + red_sm[1][3]) + (red_sm[2][3] + red_sm[3][3]);
        float4 w;
        w.x = p0 * __builtin_amdgcn_rcpf(s0);
        w.y = p1 * __builtin_amdgcn_rcpf(s1);
        w.z = p2 * __builtin_amdgcn_rcpf(s2);
        w.w = p3 * __builtin_amdgcn_rcpf(s3);
        wgt4[s] = w;
        float* ao = attn_out + (size_t)(b * kTD + t0) * kTE + s;
        ao[0]       = w.x;
        ao[kTE]     = w.y;
        ao[2 * kTE] = w.z;
        ao[3 * kTE] = w.w;
    }
    __syncthreads();

    // ---- context phase: thread = (h-float4, s-octant); float4 loads ----
    const int th4 = tid & 127;           // h quad 0..127
    const int sq  = tid >> 7;            // s octant 0..7
    const float4* enc4 = (const float4*)(enc + (size_t)b * kTE * kH);
    float4 c[TM];
    #pragma unroll
    for (int t = 0; t < TM; ++t) c[t] = float4{0.f, 0.f, 0.f, 0.f};
    #pragma unroll 4
    for (int i = 0; i < 32; ++i) {
        const int ss = sq * 32 + i;
        float4 e = enc4[(size_t)ss * 128 + th4];
        float4 w = wgt4[ss];
        c[0].x = fmaf(w.x, e.x, c[0].x); c[0].y = fmaf(w.x, e.y, c[0].y);
        c[0].z = fmaf(w.x, e.z, c[0].z); c[0].w = fmaf(w.x, e.w, c[0].w);
        c[1].x = fmaf(w.y, e.x, c[1].x); c[1].y = fmaf(w.y, e.y, c[1].y);
        c[1].z = fmaf(w.y, e.z, c[1].z); c[1].w = fmaf(w.y, e.w, c[1].w);
        c[2].x = fmaf(w.z, e.x, c[2].x); c[2].y = fmaf(w.z, e.y, c[2].y);
        c[2].z = fmaf(w.z, e.z, c[2].z); c[2].w = fmaf(w.z, e.w, c[2].w);
        c[3].x = fmaf(w.w, e.x, c[3].x); c[3].y = fmaf(w.w, e.y, c[3].y);
        c[3].z = fmaf(w.w, e.z, c[3].z); c[3].w = fmaf(w.w, e.w, c[3].w);
    }
    // tree combine: 8 -> 4 -> 1
    if (sq >= 4) {
        #pragma unroll
        for (int t = 0; t < TM; ++t) u.pctx[sq - 4][t][th4] = c[t];
    }
    __syncthreads();
    if (sq < 4) {
        #pragma unroll
        for (int t = 0; t < TM; ++t) {
            float4 p = u.pctx[sq][t][th4];
            c[t].x += p.x; c[t].y += p.y; c[t].z += p.z; c[t].w += p.w;
        }
    }
    __syncthreads();
    if (sq >= 1 && sq < 4) {
        #pragma unroll
        for (int t = 0; t < TM; ++t) u.pctx[sq - 1][t][th4] = c[t];
    }
    __syncthreads();
    if (sq == 0) {
        #pragma unroll
        for (int t = 0; t < TM; ++t) {
            float4 q0v = u.pctx[0][t][th4];
            float4 q1v = u.pctx[1][t][th4];
            float4 q2v = u.pctx[2][t][th4];
            c[t].x += (q0v.x + q1v.x) + q2v.x;
            c[t].y += (q0v.y + q1v.y) + q2v.y;
            c[t].z += (q0v.z + q1v.z) + q2v.z;
            c[t].w += (q0v.w + q1v.w) + q2v.w;
            *(float4*)&ctx_out[(size_t)(b * kTD + t0 + t) * kH + th4 * 4] = c[t];
        }
    }
}

// ---------------------------------------------------------------------------
extern "C" void kernel_launch(void* const* d_in, const int* in_sizes, int n_in,
                              void* d_out, int out_size, void* d_ws, size_t ws_size,
                              hipStream_t stream) {
    const float* enc  = (const float*)d_in[0];   // [B, TE, H]
    const float* dec  = (const float*)d_in[1];   // [B, TD, H]
    const void*  mask = d_in[2];                 // [B, TE] bool
    const float* W1   = (const float*)d_in[3];
    const float* W2   = (const float*)d_in[4];
    const float* V    = (const float*)d_in[5];   // [H, 1]

    float* ctx_out  = (float*)d_out;                     // [B, TD, H]
    float* attn_out = (float*)d_out + kB * kTD * kH;     // [B, TD, TE]

    char* ws = (char*)d_ws;
    float* mask_f = (float*)ws;                                      // 2048 f
    float* ewt    = (float*)(ws + 8192);                             // E^T packed [b][h/4][s][4]
    float* dwc    = (float*)(ws + 8192 + (size_t)kB * kTE * kH * 4); // P[t][h]

    hipLaunchKernelGGL(prep_kernel, dim3(GEMM_BLOCKS + 1), dim3(512), 0, stream,
                       enc, dec, W1, W2, mask, ewt, dwc, mask_f);
    hipLaunchKernelGGL(fused_attn_kernel, dim3(kB * kTD / TM), dim3(1024), 0, stream,
                       ewt, dwc, enc, V, mask_f, ctx_out, attn_out);
}